// Round 12
// baseline (541.042 us; speedup 1.0000x reference)
//
#include <hip/hip_runtime.h>
#include <math.h>

#define NN 50000
#define NE 800000
#define Cc 32
#define Zz 4
#define Bb 8
#define NL 2
#define DEG_INV (1.0f/16.0f)
#define SCAN_PAD 53248  // 1024 * 52
#define EBLK (NE / 256)   // 3125 edge blocks
#define NBLK (NN / 8)     // 6250 init blocks

// svb node-row (packed bf16 planar): uint[64]/node:
//   [c] = bf16(s)|bf16(v0)<<16 ; [32+c] = bf16(v1)|bf16(v2)<<16
// rec[pos] (64B aligned, dst-sorted): uint4[0]=bf16 h0[8], uint4[1]=bf16 h1[8],
//   uint4[2]=f32 Y[4], uint4[3]={src,-,-,-}
// agg node-row (planar f32): [0:32]=s, [32:64]=v0, [64:96]=v1, [96:128]=v2

__device__ __forceinline__ float ssp_f(float x) {
    float sp = fmaxf(x, 0.0f) + log1pf(expf(-fabsf(x)));
    return sp - 0.69314718055994530942f;
}
__device__ __forceinline__ float silu_f(float x) {
    return x / (1.0f + expf(-x));
}
__device__ __forceinline__ unsigned bf16rn(float f) {
    unsigned u = __float_as_uint(f);
    return (u + 0x7fffu + ((u >> 16) & 1u)) >> 16;
}

// ---------------- CSR build (once per call) ----------------

__global__ void hist_kernel(const int* __restrict__ ei, int* __restrict__ counts) {
    int e = blockIdx.x * 256 + threadIdx.x;
    if (e < NE) atomicAdd(&counts[ei[NE + e]], 1);
}

__global__ void scan_kernel(const int* __restrict__ counts,
                            int* __restrict__ base,
                            int* __restrict__ cursor) {
    __shared__ int partial[1024];
    int t = threadIdx.x;
    const int CH = 52;
    int b0 = t * CH;
    int sum = 0;
    #pragma unroll
    for (int i = 0; i < CH; i += 4) {
        int4 v = *(const int4*)(counts + b0 + i);
        sum += v.x + v.y + v.z + v.w;
    }
    partial[t] = sum;
    __syncthreads();
    for (int off = 1; off < 1024; off <<= 1) {
        int v = 0;
        if (t >= off) v = partial[t - off];
        __syncthreads();
        if (t >= off) partial[t] += v;
        __syncthreads();
    }
    int prefix = (t == 0) ? 0 : partial[t - 1];
    for (int i = b0; i < b0 + CH && i < NN; ++i) {
        base[i] = prefix;
        cursor[i] = prefix;
        prefix += counts[i];
    }
    if (t == 1023) base[NN] = partial[1023];
}

// fused: [0..EBLK): one 64B record scatter per edge (single line touch)
//        [EBLK..EBLK+NBLK): x = nf copy + svb = packed pre(x)
__global__ void prep_kernel(const int* __restrict__ ei,
                            const float* __restrict__ emb,
                            const float* __restrict__ eattr,
                            const float* __restrict__ Wr1,   // [2][8][8]
                            int* __restrict__ cursor,
                            uint4* __restrict__ rec,
                            const float* __restrict__ nf,
                            const float* __restrict__ W0,
                            const float* __restrict__ W1,
                            float* __restrict__ x,
                            unsigned* __restrict__ svb) {
    __shared__ float wr1s[128];
    __shared__ float xs[8][128];
    int t = threadIdx.x;
    int b = blockIdx.x;
    if (b < EBLK) {
        if (t < 128) wr1s[t] = Wr1[t];
        __syncthreads();
        int e = b * 256 + t;
        int src = ei[e];
        int dst = ei[NE + e];
        int pos = atomicAdd(&cursor[dst], 1);

        const float4* s4 = (const float4*)emb + (size_t)e * 2;
        float4 a = s4[0], bb = s4[1];
        float em[8] = {a.x, a.y, a.z, a.w, bb.x, bb.y, bb.z, bb.w};
        float h0[8], h1[8];
        #pragma unroll
        for (int j = 0; j < 8; ++j) {
            float acc0 = 0.f, acc1 = 0.f;
            #pragma unroll
            for (int k = 0; k < 8; ++k) {
                acc0 = fmaf(em[k], wr1s[k * 8 + j], acc0);
                acc1 = fmaf(em[k], wr1s[64 + k * 8 + j], acc1);
            }
            h0[j] = silu_f(acc0);
            h1[j] = silu_f(acc1);
        }
        uint4 u0, u1;
        u0.x = bf16rn(h0[0]) | (bf16rn(h0[1]) << 16);
        u0.y = bf16rn(h0[2]) | (bf16rn(h0[3]) << 16);
        u0.z = bf16rn(h0[4]) | (bf16rn(h0[5]) << 16);
        u0.w = bf16rn(h0[6]) | (bf16rn(h0[7]) << 16);
        u1.x = bf16rn(h1[0]) | (bf16rn(h1[1]) << 16);
        u1.y = bf16rn(h1[2]) | (bf16rn(h1[3]) << 16);
        u1.z = bf16rn(h1[4]) | (bf16rn(h1[5]) << 16);
        u1.w = bf16rn(h1[6]) | (bf16rn(h1[7]) << 16);
        uint4* r = rec + (size_t)pos * 4;
        r[0] = u0;
        r[1] = u1;
        r[2] = ((const uint4*)eattr)[e];
        r[3] = make_uint4((unsigned)src, 0u, 0u, 0u);
    } else {
        int node0 = (b - EBLK) * 8;
        #pragma unroll
        for (int k = 0; k < 4; ++k) {
            int idx = t + k * 256;
            int n = idx >> 7, col = idx & 127;
            float val = nf[(size_t)(node0 + n) * 128 + col];
            xs[n][col] = val;
            x[(size_t)(node0 + n) * 128 + col] = val;
        }
        __syncthreads();
        int n = t >> 5, f = t & 31;
        int gn = node0 + n;
        float acc_s = 0.f, a0 = 0.f, a1 = 0.f, a2 = 0.f;
        #pragma unroll
        for (int c = 0; c < Cc; ++c) {
            float w0 = W0[c * Cc + f];
            float w1 = W1[c * Cc + f];
            acc_s = fmaf(xs[n][c], w0, acc_s);
            a0 = fmaf(xs[n][32 + c * 3 + 0], w1, a0);
            a1 = fmaf(xs[n][32 + c * 3 + 1], w1, a1);
            a2 = fmaf(xs[n][32 + c * 3 + 2], w1, a2);
        }
        unsigned* o = svb + (size_t)gn * 64;
        o[f]      = bf16rn(acc_s) | (bf16rn(a0) << 16);
        o[32 + f] = bf16rn(a1)    | (bf16rn(a2) << 16);
    }
}

// process one edge: h packed bf16 in ua, Y f32, sv unpacked
#define PROC_EDGE_PK(ua, Yv, se, v0, v1, v2)                                 \
    do {                                                                     \
        float hh0 = __uint_as_float(ua.x << 16);                             \
        float hh1 = __uint_as_float(ua.x & 0xffff0000u);                     \
        float hh2 = __uint_as_float(ua.y << 16);                             \
        float hh3 = __uint_as_float(ua.y & 0xffff0000u);                     \
        float hh4 = __uint_as_float(ua.z << 16);                             \
        float hh5 = __uint_as_float(ua.z & 0xffff0000u);                     \
        float hh6 = __uint_as_float(ua.w << 16);                             \
        float hh7 = __uint_as_float(ua.w & 0xffff0000u);                     \
        float w1 = 0.f, w2 = 0.f, w3 = 0.f, w4 = 0.f, w5 = 0.f;              \
        w1 = fmaf(hh0, wr2s[0][c], w1); w2 = fmaf(hh0, wr2s[0][32 + c], w2); \
        w3 = fmaf(hh0, wr2s[0][64 + c], w3); w4 = fmaf(hh0, wr2s[0][96 + c], w4); \
        w5 = fmaf(hh0, wr2s[0][128 + c], w5);                                \
        w1 = fmaf(hh1, wr2s[1][c], w1); w2 = fmaf(hh1, wr2s[1][32 + c], w2); \
        w3 = fmaf(hh1, wr2s[1][64 + c], w3); w4 = fmaf(hh1, wr2s[1][96 + c], w4); \
        w5 = fmaf(hh1, wr2s[1][128 + c], w5);                                \
        w1 = fmaf(hh2, wr2s[2][c], w1); w2 = fmaf(hh2, wr2s[2][32 + c], w2); \
        w3 = fmaf(hh2, wr2s[2][64 + c], w3); w4 = fmaf(hh2, wr2s[2][96 + c], w4); \
        w5 = fmaf(hh2, wr2s[2][128 + c], w5);                                \
        w1 = fmaf(hh3, wr2s[3][c], w1); w2 = fmaf(hh3, wr2s[3][32 + c], w2); \
        w3 = fmaf(hh3, wr2s[3][64 + c], w3); w4 = fmaf(hh3, wr2s[3][96 + c], w4); \
        w5 = fmaf(hh3, wr2s[3][128 + c], w5);                                \
        w1 = fmaf(hh4, wr2s[4][c], w1); w2 = fmaf(hh4, wr2s[4][32 + c], w2); \
        w3 = fmaf(hh4, wr2s[4][64 + c], w3); w4 = fmaf(hh4, wr2s[4][96 + c], w4); \
        w5 = fmaf(hh4, wr2s[4][128 + c], w5);                                \
        w1 = fmaf(hh5, wr2s[5][c], w1); w2 = fmaf(hh5, wr2s[5][32 + c], w2); \
        w3 = fmaf(hh5, wr2s[5][64 + c], w3); w4 = fmaf(hh5, wr2s[5][96 + c], w4); \
        w5 = fmaf(hh5, wr2s[5][128 + c], w5);                                \
        w1 = fmaf(hh6, wr2s[6][c], w1); w2 = fmaf(hh6, wr2s[6][32 + c], w2); \
        w3 = fmaf(hh6, wr2s[6][64 + c], w3); w4 = fmaf(hh6, wr2s[6][96 + c], w4); \
        w5 = fmaf(hh6, wr2s[6][128 + c], w5);                                \
        w1 = fmaf(hh7, wr2s[7][c], w1); w2 = fmaf(hh7, wr2s[7][32 + c], w2); \
        w3 = fmaf(hh7, wr2s[7][64 + c], w3); w4 = fmaf(hh7, wr2s[7][96 + c], w4); \
        w5 = fmaf(hh7, wr2s[7][128 + c], w5);                                \
        float dot = v0 * Yv.y + v1 * Yv.z + v2 * Yv.w;                       \
        ms += w1 * se * Yv.x + w4 * dot;                                     \
        float cx = v1 * Yv.w - v2 * Yv.z;                                    \
        float cy = v2 * Yv.y - v0 * Yv.w;                                    \
        float cz = v0 * Yv.z - v1 * Yv.y;                                    \
        mv0 += w2 * se * Yv.y + w3 * v0 * Yv.x + w5 * cx;                    \
        mv1 += w2 * se * Yv.z + w3 * v1 * Yv.x + w5 * cy;                    \
        mv2 += w2 * se * Yv.w + w3 * v2 * Yv.x + w5 * cz;                    \
    } while (0)

#define UNPACK_SV(p, se, v0, v1, v2)                                         \
    unsigned ulo_##se = (p)[c], uhi_##se = (p)[32 + c];                      \
    float se = __uint_as_float(ulo_##se << 16);                              \
    float v0 = __uint_as_float(ulo_##se & 0xffff0000u);                      \
    float v1 = __uint_as_float(uhi_##se << 16);                              \
    float v2 = __uint_as_float(uhi_##se & 0xffff0000u)

// one 32-lane group per dst node; 64B records (sequential), packed-bf16 sv
__global__ void agg_kernel(const int* __restrict__ base,
                           const uint4* __restrict__ rec,
                           const int lsel,
                           const unsigned* __restrict__ svb,
                           const float* __restrict__ Wr2,
                           float* __restrict__ agg) {
    __shared__ float wr2s[8][160];
    int t = threadIdx.x;
    for (int i = t; i < 8 * 160; i += 256) ((float*)wr2s)[i] = Wr2[i];
    __syncthreads();
    int n = blockIdx.x * 8 + (t >> 5);
    int c = t & 31;
    int jb = base[n], je = base[n + 1];
    float ms = 0.f, mv0 = 0.f, mv1 = 0.f, mv2 = 0.f;

    int j = jb;
    for (; j + 1 < je; j += 2) {
        const uint4* rA = rec + (size_t)j * 4;
        const uint4* rB = rA + 4;
        uint4 uA = rA[lsel];
        float4 YA = *(const float4*)(rA + 2);
        int srcA = (int)rA[3].x;
        uint4 uB = rB[lsel];
        float4 YB = *(const float4*)(rB + 2);
        int srcB = (int)rB[3].x;
        const unsigned* pA = svb + (size_t)srcA * 64;
        const unsigned* pB = svb + (size_t)srcB * 64;
        UNPACK_SV(pA, seA, vA0, vA1, vA2);
        UNPACK_SV(pB, seB, vB0, vB1, vB2);
        PROC_EDGE_PK(uA, YA, seA, vA0, vA1, vA2);
        PROC_EDGE_PK(uB, YB, seB, vB0, vB1, vB2);
    }
    if (j < je) {
        const uint4* rA = rec + (size_t)j * 4;
        uint4 uA = rA[lsel];
        float4 YA = *(const float4*)(rA + 2);
        int srcA = (int)rA[3].x;
        const unsigned* pA = svb + (size_t)srcA * 64;
        UNPACK_SV(pA, seA, vA0, vA1, vA2);
        PROC_EDGE_PK(uA, YA, seA, vA0, vA1, vA2);
    }

    float* ap = agg + (size_t)n * 128;
    ap[c]      = ms * DEG_INV;
    ap[32 + c] = mv0 * DEG_INV;
    ap[64 + c] = mv1 * DEG_INV;
    ap[96 + c] = mv2 * DEG_INV;
}

// node_post (+ optional next-layer node_pre), 32 nodes/block, 4 nodes/thread.
template <int WANT_SV>
__global__ void post_pre_kernel(float* __restrict__ x,
                                const float* __restrict__ attrs,
                                const float* __restrict__ agg,
                                const float* __restrict__ Ws,
                                const float* __restrict__ Wv,
                                const float* __restrict__ Wsc_s,
                                const float* __restrict__ Wsc_v,
                                const float* __restrict__ W0n,
                                const float* __restrict__ W1n,
                                unsigned* __restrict__ svb) {
    __shared__ float shx[32][128];   // x, interleaved
    __shared__ float sha[32][128];   // agg, planar
    int t = threadIdx.x;
    int node0 = blockIdx.x * 32;
    #pragma unroll
    for (int k = 0; k < 4; ++k) {
        int f4 = t + k * 256;
        int n = f4 >> 5, col4 = f4 & 31;
        int gn = node0 + n;
        if (gn < NN) {
            ((float4*)&shx[n][0])[col4] = ((const float4*)(x + (size_t)gn * 128))[col4];
            ((float4*)&sha[n][0])[col4] = ((const float4*)(agg + (size_t)gn * 128))[col4];
        }
    }
    __syncthreads();
    int g = t >> 5, f = t & 31;

    float az[4][4];
    #pragma unroll
    for (int k = 0; k < 4; ++k) {
        int gn = node0 + g + k * 8;
        if (gn < NN) {
            float4 a4 = ((const float4*)attrs)[gn];
            az[k][0] = a4.x; az[k][1] = a4.y; az[k][2] = a4.z; az[k][3] = a4.w;
        } else {
            az[k][0] = az[k][1] = az[k][2] = az[k][3] = 0.f;
        }
    }

    float os0[4] = {0, 0, 0, 0}, os1[4] = {0, 0, 0, 0};
    float ov0[4] = {0, 0, 0, 0}, ov1[4] = {0, 0, 0, 0}, ov2[4] = {0, 0, 0, 0};

    #pragma unroll 2
    for (int c = 0; c < Cc; ++c) {
        float ws0 = Ws[c * 64 + f];
        float ws1 = Ws[c * 64 + 32 + f];
        float wv  = Wv[c * 32 + f];
        #pragma unroll
        for (int k = 0; k < 4; ++k) {
            int n = g + k * 8;
            float as  = sha[n][c];
            float av0 = sha[n][32 + c];
            float av1 = sha[n][64 + c];
            float av2 = sha[n][96 + c];
            os0[k] = fmaf(as, ws0, os0[k]);
            os1[k] = fmaf(as, ws1, os1[k]);
            ov0[k] = fmaf(av0, wv, ov0[k]);
            ov1[k] = fmaf(av1, wv, ov1[k]);
            ov2[k] = fmaf(av2, wv, ov2[k]);
        }
        #pragma unroll
        for (int z = 0; z < 4; ++z) {
            int cz = c * 4 + z;
            float wss0 = Wsc_s[cz * 64 + f];
            float wss1 = Wsc_s[cz * 64 + 32 + f];
            float wsv  = Wsc_v[cz * 32 + f];
            #pragma unroll
            for (int k = 0; k < 4; ++k) {
                int n = g + k * 8;
                float azv = az[k][z];
                float sa = shx[n][c] * azv;
                os0[k] = fmaf(sa, wss0, os0[k]);
                os1[k] = fmaf(sa, wss1, os1[k]);
                float va = azv * wsv;
                ov0[k] = fmaf(shx[n][32 + c * 3 + 0], va, ov0[k]);
                ov1[k] = fmaf(shx[n][32 + c * 3 + 1], va, ov1[k]);
                ov2[k] = fmaf(shx[n][32 + c * 3 + 2], va, ov2[k]);
            }
        }
    }

    float ns[4], nv0[4], nv1[4], nv2[4];
    #pragma unroll
    for (int k = 0; k < 4; ++k) {
        int n = g + k * 8;
        int gn = node0 + n;
        float feat = ssp_f(os0[k]);
        float gate = ssp_f(os1[k]);
        ns[k]  = shx[n][f] + feat;
        nv0[k] = shx[n][32 + f * 3 + 0] + ov0[k] * gate;
        nv1[k] = shx[n][32 + f * 3 + 1] + ov1[k] * gate;
        nv2[k] = shx[n][32 + f * 3 + 2] + ov2[k] * gate;
        if (gn < NN) {
            float* xp = x + (size_t)gn * 128;
            xp[f] = ns[k];
            xp[32 + f * 3 + 0] = nv0[k];
            xp[32 + f * 3 + 1] = nv1[k];
            xp[32 + f * 3 + 2] = nv2[k];
        }
    }

    if (WANT_SV) {
        __syncthreads();
        #pragma unroll
        for (int k = 0; k < 4; ++k) {
            int n = g + k * 8;
            sha[n][f] = ns[k];
            sha[n][32 + f * 3 + 0] = nv0[k];
            sha[n][32 + f * 3 + 1] = nv1[k];
            sha[n][32 + f * 3 + 2] = nv2[k];
        }
        __syncthreads();
        float bs[4] = {0, 0, 0, 0};
        float b0[4] = {0, 0, 0, 0}, b1[4] = {0, 0, 0, 0}, b2[4] = {0, 0, 0, 0};
        #pragma unroll 4
        for (int c = 0; c < Cc; ++c) {
            float w0 = W0n[c * Cc + f];
            float w1 = W1n[c * Cc + f];
            #pragma unroll
            for (int k = 0; k < 4; ++k) {
                int n = g + k * 8;
                bs[k] = fmaf(sha[n][c], w0, bs[k]);
                b0[k] = fmaf(sha[n][32 + c * 3 + 0], w1, b0[k]);
                b1[k] = fmaf(sha[n][32 + c * 3 + 1], w1, b1[k]);
                b2[k] = fmaf(sha[n][32 + c * 3 + 2], w1, b2[k]);
            }
        }
        #pragma unroll
        for (int k = 0; k < 4; ++k) {
            int gn = node0 + g + k * 8;
            if (gn < NN) {
                unsigned* o = svb + (size_t)gn * 64;
                o[f]      = bf16rn(bs[k]) | (bf16rn(b0[k]) << 16);
                o[32 + f] = bf16rn(b1[k]) | (bf16rn(b2[k]) << 16);
            }
        }
    }
}

// fallback (atomic) edge kernel — packed svb, planar agg
__global__ void edge_atomic_kernel(const int* __restrict__ ei,
                                   const float* __restrict__ emb,
                                   const float* __restrict__ eattr,
                                   const unsigned* __restrict__ svb,
                                   const float* __restrict__ Wr1,
                                   const float* __restrict__ Wr2,
                                   float* __restrict__ agg) {
    int t = threadIdx.x;
    int eg = t >> 5;
    int c = t & 31;
    int e = blockIdx.x * 8 + eg;
    if (e >= NE) return;
    int src = ei[e];
    int dst = ei[NE + e];
    float h = 0.f;
    if (c < 8) {
        #pragma unroll
        for (int k = 0; k < 8; ++k)
            h = fmaf(emb[e * 8 + k], Wr1[k * 8 + c], h);
        h = silu_f(h);
    }
    float w1 = 0.f, w2 = 0.f, w3 = 0.f, w4 = 0.f, w5 = 0.f;
    #pragma unroll
    for (int j = 0; j < 8; ++j) {
        float hj = __shfl(h, j, 32);
        const float* wr = Wr2 + j * 160;
        w1 = fmaf(hj, wr[c], w1);
        w2 = fmaf(hj, wr[32 + c], w2);
        w3 = fmaf(hj, wr[64 + c], w3);
        w4 = fmaf(hj, wr[96 + c], w4);
        w5 = fmaf(hj, wr[128 + c], w5);
    }
    float Y0  = eattr[e * 4 + 0];
    float Yv0 = eattr[e * 4 + 1];
    float Yv1 = eattr[e * 4 + 2];
    float Yv2 = eattr[e * 4 + 3];
    const unsigned* p = svb + (size_t)src * 64;
    unsigned ulo = p[c], uhi = p[32 + c];
    float se  = __uint_as_float(ulo << 16);
    float ve0 = __uint_as_float(ulo & 0xffff0000u);
    float ve1 = __uint_as_float(uhi << 16);
    float ve2 = __uint_as_float(uhi & 0xffff0000u);
    float dot = ve0 * Yv0 + ve1 * Yv1 + ve2 * Yv2;
    float msg = (w1 * se * Y0 + w4 * dot) * DEG_INV;
    float cx = ve1 * Yv2 - ve2 * Yv1;
    float cy = ve2 * Yv0 - ve0 * Yv2;
    float cz = ve0 * Yv1 - ve1 * Yv0;
    float mv0 = (w2 * se * Yv0 + w3 * ve0 * Y0 + w5 * cx) * DEG_INV;
    float mv1 = (w2 * se * Yv1 + w3 * ve1 * Y0 + w5 * cy) * DEG_INV;
    float mv2 = (w2 * se * Yv2 + w3 * ve2 * Y0 + w5 * cz) * DEG_INV;
    float* ap = agg + (size_t)dst * 128;
    atomicAdd(&ap[c], msg);
    atomicAdd(&ap[32 + c], mv0);
    atomicAdd(&ap[64 + c], mv1);
    atomicAdd(&ap[96 + c], mv2);
}

// fallback init (separate kernel, packed svb)
__global__ void init_kernel(const float* __restrict__ nf,
                            const float* __restrict__ W0,
                            const float* __restrict__ W1,
                            float* __restrict__ x,
                            unsigned* __restrict__ svb) {
    __shared__ float xs[8][128];
    int t = threadIdx.x;
    int node0 = blockIdx.x * 8;
    #pragma unroll
    for (int k = 0; k < 4; ++k) {
        int idx = t + k * 256;
        int n = idx >> 7, col = idx & 127;
        float val = nf[(size_t)(node0 + n) * 128 + col];
        xs[n][col] = val;
        x[(size_t)(node0 + n) * 128 + col] = val;
    }
    __syncthreads();
    int n = t >> 5, f = t & 31;
    int gn = node0 + n;
    float acc_s = 0.f, a0 = 0.f, a1 = 0.f, a2 = 0.f;
    #pragma unroll
    for (int c = 0; c < Cc; ++c) {
        float w0 = W0[c * Cc + f];
        float w1 = W1[c * Cc + f];
        acc_s = fmaf(xs[n][c], w0, acc_s);
        a0 = fmaf(xs[n][32 + c * 3 + 0], w1, a0);
        a1 = fmaf(xs[n][32 + c * 3 + 1], w1, a1);
        a2 = fmaf(xs[n][32 + c * 3 + 2], w1, a2);
    }
    unsigned* o = svb + (size_t)gn * 64;
    o[f]      = bf16rn(acc_s) | (bf16rn(a0) << 16);
    o[32 + f] = bf16rn(a1)    | (bf16rn(a2) << 16);
}

extern "C" void kernel_launch(void* const* d_in, const int* in_sizes, int n_in,
                              void* d_out, int out_size, void* d_ws, size_t ws_size,
                              hipStream_t stream) {
    const float* node_features  = (const float*)d_in[0];
    const float* node_attrs     = (const float*)d_in[1];
    const int*   edge_index     = (const int*)d_in[2];
    const float* edge_embedding = (const float*)d_in[3];
    const float* edge_attrs     = (const float*)d_in[4];
    const float* W0    = (const float*)d_in[5];
    const float* W1    = (const float*)d_in[6];
    const float* Wr1   = (const float*)d_in[7];
    const float* Wr2   = (const float*)d_in[8];
    const float* Ws    = (const float*)d_in[9];
    const float* Wv    = (const float*)d_in[10];
    const float* Wsc_s = (const float*)d_in[11];
    const float* Wsc_v = (const float*)d_in[12];

    float* x = (float*)d_out;

    float* ws = (float*)d_ws;
    unsigned* svb = (unsigned*)ws;                     // NN*64 uint (packed bf16)
    float* agg  = (float*)(svb + (size_t)NN * 64);     // NN*128 f32 (planar)
    uint4* rec  = (uint4*)(agg + (size_t)NN * 128);    // NE*4 uint4 (64B/edge)
    int* counts   = (int*)(rec + (size_t)NE * 4);      // SCAN_PAD
    int* base     = counts + SCAN_PAD;                 // NN+1
    int* cursor   = base + NN + 1;                     // NN
    size_t needed = ((char*)(cursor + NN)) - (char*)d_ws;

    bool use_sorted = ws_size >= needed;
    const int PP_GRID = (NN + 31) / 32;

    if (use_sorted) {
        hipMemsetAsync(counts, 0, SCAN_PAD * sizeof(int), stream);
        hist_kernel<<<NE / 256, 256, 0, stream>>>(edge_index, counts);
        scan_kernel<<<1, 1024, 0, stream>>>(counts, base, cursor);
        prep_kernel<<<EBLK + NBLK, 256, 0, stream>>>(
            edge_index, edge_embedding, edge_attrs, Wr1,
            cursor, rec,
            node_features, W0, W1, x, svb);

        // layer 0
        agg_kernel<<<NN / 8, 256, 0, stream>>>(base, rec, 0, svb, Wr2, agg);
        post_pre_kernel<1><<<PP_GRID, 256, 0, stream>>>(
            x, node_attrs, agg, Ws, Wv, Wsc_s, Wsc_v,
            W0 + Cc * Cc, W1 + Cc * Cc, svb);
        // layer 1
        agg_kernel<<<NN / 8, 256, 0, stream>>>(base, rec, 1, svb,
                                               Wr2 + Bb * 5 * Cc, agg);
        post_pre_kernel<0><<<PP_GRID, 256, 0, stream>>>(
            x, node_attrs, agg,
            Ws + Cc * 2 * Cc, Wv + Cc * Cc,
            Wsc_s + Cc * Zz * 2 * Cc, Wsc_v + Cc * Zz * Cc,
            nullptr, nullptr, nullptr);
    } else {
        hipMemcpyAsync(x, node_features, (size_t)NN * 128 * sizeof(float),
                       hipMemcpyDeviceToDevice, stream);
        for (int l = 0; l < NL; ++l) {
            hipMemsetAsync(agg, 0, (size_t)NN * 128 * sizeof(float), stream);
            init_kernel<<<NN / 8, 256, 0, stream>>>(
                x, W0 + l * Cc * Cc, W1 + l * Cc * Cc, x, svb);
            edge_atomic_kernel<<<NE / 8, 256, 0, stream>>>(
                edge_index, edge_embedding, edge_attrs, svb,
                Wr1 + l * Bb * Bb, Wr2 + l * Bb * 5 * Cc, agg);
            post_pre_kernel<0><<<PP_GRID, 256, 0, stream>>>(
                x, node_attrs, agg,
                Ws + l * Cc * 2 * Cc, Wv + l * Cc * Cc,
                Wsc_s + l * Cc * Zz * 2 * Cc, Wsc_v + l * Cc * Zz * Cc,
                nullptr, nullptr, nullptr);
        }
    }
}

// Round 13
// 533.060 us; speedup vs baseline: 1.0150x; 1.0150x over previous
//
#include <hip/hip_runtime.h>
#include <math.h>

#define NN 50000
#define NE 800000
#define Cc 32
#define Zz 4
#define Bb 8
#define NL 2
#define DEG_INV (1.0f/16.0f)
#define SCAN_PAD 53248  // 1024 * 52
#define EBLK (NE / 256)   // 3125 edge blocks
#define NBLK (NN / 8)     // 6250 init blocks

// svb node-row (packed bf16 planar): uint[64]/node:
//   [c] = bf16(s)|bf16(v0)<<16 ; [32+c] = bf16(v1)|bf16(v2)<<16
// rec[pos] (64B aligned, dst-sorted): uint4[0]=bf16 h0[8], uint4[1]=bf16 h1[8],
//   uint4[2]=f32 Y[4], uint4[3]={src,-,-,-}
// agg node-row (planar f32): [0:32]=s, [32:64]=v0, [64:96]=v1, [96:128]=v2

__device__ __forceinline__ float ssp_f(float x) {
    float sp = fmaxf(x, 0.0f) + log1pf(expf(-fabsf(x)));
    return sp - 0.69314718055994530942f;
}
__device__ __forceinline__ float silu_f(float x) {
    return x / (1.0f + expf(-x));
}
__device__ __forceinline__ unsigned bf16rn(float f) {
    unsigned u = __float_as_uint(f);
    return (u + 0x7fffu + ((u >> 16) & 1u)) >> 16;
}

// ---------------- CSR build (once per call) ----------------

__global__ void hist_kernel(const int* __restrict__ ei, int* __restrict__ counts) {
    int e = blockIdx.x * 256 + threadIdx.x;
    if (e < NE) atomicAdd(&counts[ei[NE + e]], 1);
}

__global__ void scan_kernel(const int* __restrict__ counts,
                            int* __restrict__ base,
                            int* __restrict__ cursor) {
    __shared__ int partial[1024];
    int t = threadIdx.x;
    const int CH = 52;
    int b0 = t * CH;
    int sum = 0;
    #pragma unroll
    for (int i = 0; i < CH; i += 4) {
        int4 v = *(const int4*)(counts + b0 + i);
        sum += v.x + v.y + v.z + v.w;
    }
    partial[t] = sum;
    __syncthreads();
    for (int off = 1; off < 1024; off <<= 1) {
        int v = 0;
        if (t >= off) v = partial[t - off];
        __syncthreads();
        if (t >= off) partial[t] += v;
        __syncthreads();
    }
    int prefix = (t == 0) ? 0 : partial[t - 1];
    for (int i = b0; i < b0 + CH && i < NN; ++i) {
        base[i] = prefix;
        cursor[i] = prefix;
        prefix += counts[i];
    }
    if (t == 1023) base[NN] = partial[1023];
}

// fused: [0..EBLK): one 64B record scatter per edge (single line touch)
//        [EBLK..EBLK+NBLK): x = nf copy + svb = packed pre(x)
__global__ void prep_kernel(const int* __restrict__ ei,
                            const float* __restrict__ emb,
                            const float* __restrict__ eattr,
                            const float* __restrict__ Wr1,   // [2][8][8]
                            int* __restrict__ cursor,
                            uint4* __restrict__ rec,
                            const float* __restrict__ nf,
                            const float* __restrict__ W0,
                            const float* __restrict__ W1,
                            float* __restrict__ x,
                            unsigned* __restrict__ svb) {
    __shared__ float wr1s[128];
    __shared__ float xs[8][128];
    int t = threadIdx.x;
    int b = blockIdx.x;
    if (b < EBLK) {
        if (t < 128) wr1s[t] = Wr1[t];
        __syncthreads();
        int e = b * 256 + t;
        int src = ei[e];
        int dst = ei[NE + e];
        int pos = atomicAdd(&cursor[dst], 1);

        const float4* s4 = (const float4*)emb + (size_t)e * 2;
        float4 a = s4[0], bb = s4[1];
        float em[8] = {a.x, a.y, a.z, a.w, bb.x, bb.y, bb.z, bb.w};
        float h0[8], h1[8];
        #pragma unroll
        for (int j = 0; j < 8; ++j) {
            float acc0 = 0.f, acc1 = 0.f;
            #pragma unroll
            for (int k = 0; k < 8; ++k) {
                acc0 = fmaf(em[k], wr1s[k * 8 + j], acc0);
                acc1 = fmaf(em[k], wr1s[64 + k * 8 + j], acc1);
            }
            h0[j] = silu_f(acc0);
            h1[j] = silu_f(acc1);
        }
        uint4 u0, u1;
        u0.x = bf16rn(h0[0]) | (bf16rn(h0[1]) << 16);
        u0.y = bf16rn(h0[2]) | (bf16rn(h0[3]) << 16);
        u0.z = bf16rn(h0[4]) | (bf16rn(h0[5]) << 16);
        u0.w = bf16rn(h0[6]) | (bf16rn(h0[7]) << 16);
        u1.x = bf16rn(h1[0]) | (bf16rn(h1[1]) << 16);
        u1.y = bf16rn(h1[2]) | (bf16rn(h1[3]) << 16);
        u1.z = bf16rn(h1[4]) | (bf16rn(h1[5]) << 16);
        u1.w = bf16rn(h1[6]) | (bf16rn(h1[7]) << 16);
        uint4* r = rec + (size_t)pos * 4;
        r[0] = u0;
        r[1] = u1;
        r[2] = ((const uint4*)eattr)[e];
        r[3] = make_uint4((unsigned)src, 0u, 0u, 0u);
    } else {
        int node0 = (b - EBLK) * 8;
        #pragma unroll
        for (int k = 0; k < 4; ++k) {
            int idx = t + k * 256;
            int n = idx >> 7, col = idx & 127;
            float val = nf[(size_t)(node0 + n) * 128 + col];
            xs[n][col] = val;
            x[(size_t)(node0 + n) * 128 + col] = val;
        }
        __syncthreads();
        int n = t >> 5, f = t & 31;
        int gn = node0 + n;
        float acc_s = 0.f, a0 = 0.f, a1 = 0.f, a2 = 0.f;
        #pragma unroll
        for (int c = 0; c < Cc; ++c) {
            float w0 = W0[c * Cc + f];
            float w1 = W1[c * Cc + f];
            acc_s = fmaf(xs[n][c], w0, acc_s);
            a0 = fmaf(xs[n][32 + c * 3 + 0], w1, a0);
            a1 = fmaf(xs[n][32 + c * 3 + 1], w1, a1);
            a2 = fmaf(xs[n][32 + c * 3 + 2], w1, a2);
        }
        unsigned* o = svb + (size_t)gn * 64;
        o[f]      = bf16rn(acc_s) | (bf16rn(a0) << 16);
        o[32 + f] = bf16rn(a1)    | (bf16rn(a2) << 16);
    }
}

// process one edge: h packed bf16 in ua, Y f32, sv unpacked
#define PROC_EDGE_PK(ua, Yv, se, v0, v1, v2)                                 \
    do {                                                                     \
        float hh0 = __uint_as_float(ua.x << 16);                             \
        float hh1 = __uint_as_float(ua.x & 0xffff0000u);                     \
        float hh2 = __uint_as_float(ua.y << 16);                             \
        float hh3 = __uint_as_float(ua.y & 0xffff0000u);                     \
        float hh4 = __uint_as_float(ua.z << 16);                             \
        float hh5 = __uint_as_float(ua.z & 0xffff0000u);                     \
        float hh6 = __uint_as_float(ua.w << 16);                             \
        float hh7 = __uint_as_float(ua.w & 0xffff0000u);                     \
        float w1 = 0.f, w2 = 0.f, w3 = 0.f, w4 = 0.f, w5 = 0.f;              \
        w1 = fmaf(hh0, wr2s[0][c], w1); w2 = fmaf(hh0, wr2s[0][32 + c], w2); \
        w3 = fmaf(hh0, wr2s[0][64 + c], w3); w4 = fmaf(hh0, wr2s[0][96 + c], w4); \
        w5 = fmaf(hh0, wr2s[0][128 + c], w5);                                \
        w1 = fmaf(hh1, wr2s[1][c], w1); w2 = fmaf(hh1, wr2s[1][32 + c], w2); \
        w3 = fmaf(hh1, wr2s[1][64 + c], w3); w4 = fmaf(hh1, wr2s[1][96 + c], w4); \
        w5 = fmaf(hh1, wr2s[1][128 + c], w5);                                \
        w1 = fmaf(hh2, wr2s[2][c], w1); w2 = fmaf(hh2, wr2s[2][32 + c], w2); \
        w3 = fmaf(hh2, wr2s[2][64 + c], w3); w4 = fmaf(hh2, wr2s[2][96 + c], w4); \
        w5 = fmaf(hh2, wr2s[2][128 + c], w5);                                \
        w1 = fmaf(hh3, wr2s[3][c], w1); w2 = fmaf(hh3, wr2s[3][32 + c], w2); \
        w3 = fmaf(hh3, wr2s[3][64 + c], w3); w4 = fmaf(hh3, wr2s[3][96 + c], w4); \
        w5 = fmaf(hh3, wr2s[3][128 + c], w5);                                \
        w1 = fmaf(hh4, wr2s[4][c], w1); w2 = fmaf(hh4, wr2s[4][32 + c], w2); \
        w3 = fmaf(hh4, wr2s[4][64 + c], w3); w4 = fmaf(hh4, wr2s[4][96 + c], w4); \
        w5 = fmaf(hh4, wr2s[4][128 + c], w5);                                \
        w1 = fmaf(hh5, wr2s[5][c], w1); w2 = fmaf(hh5, wr2s[5][32 + c], w2); \
        w3 = fmaf(hh5, wr2s[5][64 + c], w3); w4 = fmaf(hh5, wr2s[5][96 + c], w4); \
        w5 = fmaf(hh5, wr2s[5][128 + c], w5);                                \
        w1 = fmaf(hh6, wr2s[6][c], w1); w2 = fmaf(hh6, wr2s[6][32 + c], w2); \
        w3 = fmaf(hh6, wr2s[6][64 + c], w3); w4 = fmaf(hh6, wr2s[6][96 + c], w4); \
        w5 = fmaf(hh6, wr2s[6][128 + c], w5);                                \
        w1 = fmaf(hh7, wr2s[7][c], w1); w2 = fmaf(hh7, wr2s[7][32 + c], w2); \
        w3 = fmaf(hh7, wr2s[7][64 + c], w3); w4 = fmaf(hh7, wr2s[7][96 + c], w4); \
        w5 = fmaf(hh7, wr2s[7][128 + c], w5);                                \
        float dot = v0 * Yv.y + v1 * Yv.z + v2 * Yv.w;                       \
        ms += w1 * se * Yv.x + w4 * dot;                                     \
        float cx = v1 * Yv.w - v2 * Yv.z;                                    \
        float cy = v2 * Yv.y - v0 * Yv.w;                                    \
        float cz = v0 * Yv.z - v1 * Yv.y;                                    \
        mv0 += w2 * se * Yv.y + w3 * v0 * Yv.x + w5 * cx;                    \
        mv1 += w2 * se * Yv.z + w3 * v1 * Yv.x + w5 * cy;                    \
        mv2 += w2 * se * Yv.w + w3 * v2 * Yv.x + w5 * cz;                    \
    } while (0)

#define UNPACK_SV(p, se, v0, v1, v2)                                         \
    unsigned ulo_##se = (p)[c], uhi_##se = (p)[32 + c];                      \
    float se = __uint_as_float(ulo_##se << 16);                              \
    float v0 = __uint_as_float(ulo_##se & 0xffff0000u);                      \
    float v1 = __uint_as_float(uhi_##se << 16);                              \
    float v2 = __uint_as_float(uhi_##se & 0xffff0000u)

// one 32-lane group per dst node; 64B records (sequential), packed-bf16 sv
__global__ void agg_kernel(const int* __restrict__ base,
                           const uint4* __restrict__ rec,
                           const int lsel,
                           const unsigned* __restrict__ svb,
                           const float* __restrict__ Wr2,
                           float* __restrict__ agg) {
    __shared__ float wr2s[8][160];
    int t = threadIdx.x;
    for (int i = t; i < 8 * 160; i += 256) ((float*)wr2s)[i] = Wr2[i];
    __syncthreads();
    int n = blockIdx.x * 8 + (t >> 5);
    int c = t & 31;
    int jb = base[n], je = base[n + 1];
    float ms = 0.f, mv0 = 0.f, mv1 = 0.f, mv2 = 0.f;

    int j = jb;
    for (; j + 1 < je; j += 2) {
        const uint4* rA = rec + (size_t)j * 4;
        const uint4* rB = rA + 4;
        uint4 uA = rA[lsel];
        float4 YA = *(const float4*)(rA + 2);
        int srcA = (int)rA[3].x;
        uint4 uB = rB[lsel];
        float4 YB = *(const float4*)(rB + 2);
        int srcB = (int)rB[3].x;
        const unsigned* pA = svb + (size_t)srcA * 64;
        const unsigned* pB = svb + (size_t)srcB * 64;
        UNPACK_SV(pA, seA, vA0, vA1, vA2);
        UNPACK_SV(pB, seB, vB0, vB1, vB2);
        PROC_EDGE_PK(uA, YA, seA, vA0, vA1, vA2);
        PROC_EDGE_PK(uB, YB, seB, vB0, vB1, vB2);
    }
    if (j < je) {
        const uint4* rA = rec + (size_t)j * 4;
        uint4 uA = rA[lsel];
        float4 YA = *(const float4*)(rA + 2);
        int srcA = (int)rA[3].x;
        const unsigned* pA = svb + (size_t)srcA * 64;
        UNPACK_SV(pA, seA, vA0, vA1, vA2);
        PROC_EDGE_PK(uA, YA, seA, vA0, vA1, vA2);
    }

    float* ap = agg + (size_t)n * 128;
    ap[c]      = ms * DEG_INV;
    ap[32 + c] = mv0 * DEG_INV;
    ap[64 + c] = mv1 * DEG_INV;
    ap[96 + c] = mv2 * DEG_INV;
}

// node_post (+ optional next-layer node_pre), 16 nodes/block, 128 threads,
// 4 nodes/thread (n = g + k*4, g in 0..3). LDS 16KB -> ~10 blocks/CU.
template <int WANT_SV>
__global__ void post_pre_kernel(float* __restrict__ x,
                                const float* __restrict__ attrs,
                                const float* __restrict__ agg,
                                const float* __restrict__ Ws,
                                const float* __restrict__ Wv,
                                const float* __restrict__ Wsc_s,
                                const float* __restrict__ Wsc_v,
                                const float* __restrict__ W0n,
                                const float* __restrict__ W1n,
                                unsigned* __restrict__ svb) {
    __shared__ float shx[16][128];   // x, interleaved
    __shared__ float sha[16][128];   // agg, planar
    int t = threadIdx.x;
    int node0 = blockIdx.x * 16;
    #pragma unroll
    for (int k = 0; k < 4; ++k) {
        int f4 = t + k * 128;          // 0..511 float4 slots (16 nodes x 32)
        int n = f4 >> 5, col4 = f4 & 31;
        int gn = node0 + n;
        if (gn < NN) {
            ((float4*)&shx[n][0])[col4] = ((const float4*)(x + (size_t)gn * 128))[col4];
            ((float4*)&sha[n][0])[col4] = ((const float4*)(agg + (size_t)gn * 128))[col4];
        }
    }
    __syncthreads();
    int g = t >> 5, f = t & 31;        // g in 0..3

    float az[4][4];
    #pragma unroll
    for (int k = 0; k < 4; ++k) {
        int gn = node0 + g + k * 4;
        if (gn < NN) {
            float4 a4 = ((const float4*)attrs)[gn];
            az[k][0] = a4.x; az[k][1] = a4.y; az[k][2] = a4.z; az[k][3] = a4.w;
        } else {
            az[k][0] = az[k][1] = az[k][2] = az[k][3] = 0.f;
        }
    }

    float os0[4] = {0, 0, 0, 0}, os1[4] = {0, 0, 0, 0};
    float ov0[4] = {0, 0, 0, 0}, ov1[4] = {0, 0, 0, 0}, ov2[4] = {0, 0, 0, 0};

    #pragma unroll 2
    for (int c = 0; c < Cc; ++c) {
        float ws0 = Ws[c * 64 + f];
        float ws1 = Ws[c * 64 + 32 + f];
        float wv  = Wv[c * 32 + f];
        #pragma unroll
        for (int k = 0; k < 4; ++k) {
            int n = g + k * 4;
            float as  = sha[n][c];
            float av0 = sha[n][32 + c];
            float av1 = sha[n][64 + c];
            float av2 = sha[n][96 + c];
            os0[k] = fmaf(as, ws0, os0[k]);
            os1[k] = fmaf(as, ws1, os1[k]);
            ov0[k] = fmaf(av0, wv, ov0[k]);
            ov1[k] = fmaf(av1, wv, ov1[k]);
            ov2[k] = fmaf(av2, wv, ov2[k]);
        }
        #pragma unroll
        for (int z = 0; z < 4; ++z) {
            int cz = c * 4 + z;
            float wss0 = Wsc_s[cz * 64 + f];
            float wss1 = Wsc_s[cz * 64 + 32 + f];
            float wsv  = Wsc_v[cz * 32 + f];
            #pragma unroll
            for (int k = 0; k < 4; ++k) {
                int n = g + k * 4;
                float azv = az[k][z];
                float sa = shx[n][c] * azv;
                os0[k] = fmaf(sa, wss0, os0[k]);
                os1[k] = fmaf(sa, wss1, os1[k]);
                float va = azv * wsv;
                ov0[k] = fmaf(shx[n][32 + c * 3 + 0], va, ov0[k]);
                ov1[k] = fmaf(shx[n][32 + c * 3 + 1], va, ov1[k]);
                ov2[k] = fmaf(shx[n][32 + c * 3 + 2], va, ov2[k]);
            }
        }
    }

    float ns[4], nv0[4], nv1[4], nv2[4];
    #pragma unroll
    for (int k = 0; k < 4; ++k) {
        int n = g + k * 4;
        int gn = node0 + n;
        float feat = ssp_f(os0[k]);
        float gate = ssp_f(os1[k]);
        ns[k]  = shx[n][f] + feat;
        nv0[k] = shx[n][32 + f * 3 + 0] + ov0[k] * gate;
        nv1[k] = shx[n][32 + f * 3 + 1] + ov1[k] * gate;
        nv2[k] = shx[n][32 + f * 3 + 2] + ov2[k] * gate;
        if (gn < NN) {
            float* xp = x + (size_t)gn * 128;
            xp[f] = ns[k];
            xp[32 + f * 3 + 0] = nv0[k];
            xp[32 + f * 3 + 1] = nv1[k];
            xp[32 + f * 3 + 2] = nv2[k];
        }
    }

    if (WANT_SV) {
        __syncthreads();
        #pragma unroll
        for (int k = 0; k < 4; ++k) {
            int n = g + k * 4;
            sha[n][f] = ns[k];
            sha[n][32 + f * 3 + 0] = nv0[k];
            sha[n][32 + f * 3 + 1] = nv1[k];
            sha[n][32 + f * 3 + 2] = nv2[k];
        }
        __syncthreads();
        float bs[4] = {0, 0, 0, 0};
        float b0[4] = {0, 0, 0, 0}, b1[4] = {0, 0, 0, 0}, b2[4] = {0, 0, 0, 0};
        #pragma unroll 4
        for (int c = 0; c < Cc; ++c) {
            float w0 = W0n[c * Cc + f];
            float w1 = W1n[c * Cc + f];
            #pragma unroll
            for (int k = 0; k < 4; ++k) {
                int n = g + k * 4;
                bs[k] = fmaf(sha[n][c], w0, bs[k]);
                b0[k] = fmaf(sha[n][32 + c * 3 + 0], w1, b0[k]);
                b1[k] = fmaf(sha[n][32 + c * 3 + 1], w1, b1[k]);
                b2[k] = fmaf(sha[n][32 + c * 3 + 2], w1, b2[k]);
            }
        }
        #pragma unroll
        for (int k = 0; k < 4; ++k) {
            int gn = node0 + g + k * 4;
            if (gn < NN) {
                unsigned* o = svb + (size_t)gn * 64;
                o[f]      = bf16rn(bs[k]) | (bf16rn(b0[k]) << 16);
                o[32 + f] = bf16rn(b1[k]) | (bf16rn(b2[k]) << 16);
            }
        }
    }
}

// fallback (atomic) edge kernel — packed svb, planar agg
__global__ void edge_atomic_kernel(const int* __restrict__ ei,
                                   const float* __restrict__ emb,
                                   const float* __restrict__ eattr,
                                   const unsigned* __restrict__ svb,
                                   const float* __restrict__ Wr1,
                                   const float* __restrict__ Wr2,
                                   float* __restrict__ agg) {
    int t = threadIdx.x;
    int eg = t >> 5;
    int c = t & 31;
    int e = blockIdx.x * 8 + eg;
    if (e >= NE) return;
    int src = ei[e];
    int dst = ei[NE + e];
    float h = 0.f;
    if (c < 8) {
        #pragma unroll
        for (int k = 0; k < 8; ++k)
            h = fmaf(emb[e * 8 + k], Wr1[k * 8 + c], h);
        h = silu_f(h);
    }
    float w1 = 0.f, w2 = 0.f, w3 = 0.f, w4 = 0.f, w5 = 0.f;
    #pragma unroll
    for (int j = 0; j < 8; ++j) {
        float hj = __shfl(h, j, 32);
        const float* wr = Wr2 + j * 160;
        w1 = fmaf(hj, wr[c], w1);
        w2 = fmaf(hj, wr[32 + c], w2);
        w3 = fmaf(hj, wr[64 + c], w3);
        w4 = fmaf(hj, wr[96 + c], w4);
        w5 = fmaf(hj, wr[128 + c], w5);
    }
    float Y0  = eattr[e * 4 + 0];
    float Yv0 = eattr[e * 4 + 1];
    float Yv1 = eattr[e * 4 + 2];
    float Yv2 = eattr[e * 4 + 3];
    const unsigned* p = svb + (size_t)src * 64;
    unsigned ulo = p[c], uhi = p[32 + c];
    float se  = __uint_as_float(ulo << 16);
    float ve0 = __uint_as_float(ulo & 0xffff0000u);
    float ve1 = __uint_as_float(uhi << 16);
    float ve2 = __uint_as_float(uhi & 0xffff0000u);
    float dot = ve0 * Yv0 + ve1 * Yv1 + ve2 * Yv2;
    float msg = (w1 * se * Y0 + w4 * dot) * DEG_INV;
    float cx = ve1 * Yv2 - ve2 * Yv1;
    float cy = ve2 * Yv0 - ve0 * Yv2;
    float cz = ve0 * Yv1 - ve1 * Yv0;
    float mv0 = (w2 * se * Yv0 + w3 * ve0 * Y0 + w5 * cx) * DEG_INV;
    float mv1 = (w2 * se * Yv1 + w3 * ve1 * Y0 + w5 * cy) * DEG_INV;
    float mv2 = (w2 * se * Yv2 + w3 * ve2 * Y0 + w5 * cz) * DEG_INV;
    float* ap = agg + (size_t)dst * 128;
    atomicAdd(&ap[c], msg);
    atomicAdd(&ap[32 + c], mv0);
    atomicAdd(&ap[64 + c], mv1);
    atomicAdd(&ap[96 + c], mv2);
}

// fallback init (separate kernel, packed svb)
__global__ void init_kernel(const float* __restrict__ nf,
                            const float* __restrict__ W0,
                            const float* __restrict__ W1,
                            float* __restrict__ x,
                            unsigned* __restrict__ svb) {
    __shared__ float xs[8][128];
    int t = threadIdx.x;
    int node0 = blockIdx.x * 8;
    #pragma unroll
    for (int k = 0; k < 4; ++k) {
        int idx = t + k * 256;
        int n = idx >> 7, col = idx & 127;
        float val = nf[(size_t)(node0 + n) * 128 + col];
        xs[n][col] = val;
        x[(size_t)(node0 + n) * 128 + col] = val;
    }
    __syncthreads();
    int n = t >> 5, f = t & 31;
    int gn = node0 + n;
    float acc_s = 0.f, a0 = 0.f, a1 = 0.f, a2 = 0.f;
    #pragma unroll
    for (int c = 0; c < Cc; ++c) {
        float w0 = W0[c * Cc + f];
        float w1 = W1[c * Cc + f];
        acc_s = fmaf(xs[n][c], w0, acc_s);
        a0 = fmaf(xs[n][32 + c * 3 + 0], w1, a0);
        a1 = fmaf(xs[n][32 + c * 3 + 1], w1, a1);
        a2 = fmaf(xs[n][32 + c * 3 + 2], w1, a2);
    }
    unsigned* o = svb + (size_t)gn * 64;
    o[f]      = bf16rn(acc_s) | (bf16rn(a0) << 16);
    o[32 + f] = bf16rn(a1)    | (bf16rn(a2) << 16);
}

extern "C" void kernel_launch(void* const* d_in, const int* in_sizes, int n_in,
                              void* d_out, int out_size, void* d_ws, size_t ws_size,
                              hipStream_t stream) {
    const float* node_features  = (const float*)d_in[0];
    const float* node_attrs     = (const float*)d_in[1];
    const int*   edge_index     = (const int*)d_in[2];
    const float* edge_embedding = (const float*)d_in[3];
    const float* edge_attrs     = (const float*)d_in[4];
    const float* W0    = (const float*)d_in[5];
    const float* W1    = (const float*)d_in[6];
    const float* Wr1   = (const float*)d_in[7];
    const float* Wr2   = (const float*)d_in[8];
    const float* Ws    = (const float*)d_in[9];
    const float* Wv    = (const float*)d_in[10];
    const float* Wsc_s = (const float*)d_in[11];
    const float* Wsc_v = (const float*)d_in[12];

    float* x = (float*)d_out;

    float* ws = (float*)d_ws;
    unsigned* svb = (unsigned*)ws;                     // NN*64 uint (packed bf16)
    float* agg  = (float*)(svb + (size_t)NN * 64);     // NN*128 f32 (planar)
    uint4* rec  = (uint4*)(agg + (size_t)NN * 128);    // NE*4 uint4 (64B/edge)
    int* counts   = (int*)(rec + (size_t)NE * 4);      // SCAN_PAD
    int* base     = counts + SCAN_PAD;                 // NN+1
    int* cursor   = base + NN + 1;                     // NN
    size_t needed = ((char*)(cursor + NN)) - (char*)d_ws;

    bool use_sorted = ws_size >= needed;
    const int PP_GRID = (NN + 15) / 16;

    if (use_sorted) {
        hipMemsetAsync(counts, 0, SCAN_PAD * sizeof(int), stream);
        hist_kernel<<<NE / 256, 256, 0, stream>>>(edge_index, counts);
        scan_kernel<<<1, 1024, 0, stream>>>(counts, base, cursor);
        prep_kernel<<<EBLK + NBLK, 256, 0, stream>>>(
            edge_index, edge_embedding, edge_attrs, Wr1,
            cursor, rec,
            node_features, W0, W1, x, svb);

        // layer 0
        agg_kernel<<<NN / 8, 256, 0, stream>>>(base, rec, 0, svb, Wr2, agg);
        post_pre_kernel<1><<<PP_GRID, 128, 0, stream>>>(
            x, node_attrs, agg, Ws, Wv, Wsc_s, Wsc_v,
            W0 + Cc * Cc, W1 + Cc * Cc, svb);
        // layer 1
        agg_kernel<<<NN / 8, 256, 0, stream>>>(base, rec, 1, svb,
                                               Wr2 + Bb * 5 * Cc, agg);
        post_pre_kernel<0><<<PP_GRID, 128, 0, stream>>>(
            x, node_attrs, agg,
            Ws + Cc * 2 * Cc, Wv + Cc * Cc,
            Wsc_s + Cc * Zz * 2 * Cc, Wsc_v + Cc * Zz * Cc,
            nullptr, nullptr, nullptr);
    } else {
        hipMemcpyAsync(x, node_features, (size_t)NN * 128 * sizeof(float),
                       hipMemcpyDeviceToDevice, stream);
        for (int l = 0; l < NL; ++l) {
            hipMemsetAsync(agg, 0, (size_t)NN * 128 * sizeof(float), stream);
            init_kernel<<<NN / 8, 256, 0, stream>>>(
                x, W0 + l * Cc * Cc, W1 + l * Cc * Cc, x, svb);
            edge_atomic_kernel<<<NE / 8, 256, 0, stream>>>(
                edge_index, edge_embedding, edge_attrs, svb,
                Wr1 + l * Bb * Bb, Wr2 + l * Bb * 5 * Cc, agg);
            post_pre_kernel<0><<<PP_GRID, 128, 0, stream>>>(
                x, node_attrs, agg,
                Ws + l * Cc * 2 * Cc, Wv + l * Cc * Cc,
                Wsc_s + l * Cc * Zz * 2 * Cc, Wsc_v + l * Cc * Zz * Cc,
                nullptr, nullptr, nullptr);
        }
    }
}

// Round 14
// 440.390 us; speedup vs baseline: 1.2286x; 1.2104x over previous
//
#include <hip/hip_runtime.h>
#include <math.h>

#define NN 50000
#define NE 800000
#define Cc 32
#define Zz 4
#define Bb 8
#define NL 2
#define DEG_INV (1.0f/16.0f)
#define SCAN_PAD 53248      // >= SCAN_BLOCKS*1024, int4-aligned
#define SCAN_BLOCKS 49      // 49*1024 = 50176 >= NN
#define EBLK (NE / 256)     // 3125 edge blocks
#define NBLK (NN / 8)       // 6250 init blocks

// svb node-row (packed bf16 planar): uint[64]/node:
//   [c] = bf16(s)|bf16(v0)<<16 ; [32+c] = bf16(v1)|bf16(v2)<<16
// rec[pos] (64B aligned, dst-sorted): uint4[0]=bf16 h0[8], uint4[1]=bf16 h1[8],
//   uint4[2]=f32 Y[4], uint4[3]={src,-,-,-}
// agg node-row (planar f32): [0:32]=s, [32:64]=v0, [64:96]=v1, [96:128]=v2

__device__ __forceinline__ float ssp_f(float x) {
    float sp = fmaxf(x, 0.0f) + log1pf(expf(-fabsf(x)));
    return sp - 0.69314718055994530942f;
}
__device__ __forceinline__ float silu_f(float x) {
    return x / (1.0f + expf(-x));
}
__device__ __forceinline__ unsigned bf16rn(float f) {
    unsigned u = __float_as_uint(f);
    return (u + 0x7fffu + ((u >> 16) & 1u)) >> 16;
}

// ---------------- CSR build (once per call) ----------------

__global__ void hist_kernel(const int* __restrict__ ei, int* __restrict__ counts) {
    int e = blockIdx.x * 256 + threadIdx.x;
    if (e < NE) atomicAdd(&counts[ei[NE + e]], 1);
}

// phase 1: per-block sums (coalesced int4 loads)
__global__ void scan_part_kernel(const int* __restrict__ counts,
                                 int* __restrict__ blocksum) {
    __shared__ int red[256];
    int b = blockIdx.x, t = threadIdx.x;
    int4 v = ((const int4*)counts)[b * 256 + t];
    red[t] = v.x + v.y + v.z + v.w;
    __syncthreads();
    for (int off = 128; off > 0; off >>= 1) {
        if (t < off) red[t] += red[t + off];
        __syncthreads();
    }
    if (t == 0) blocksum[b] = red[0];
}

// phase 2: exclusive scan of 49 block sums (one wave), base[NN]=NE
__global__ void scan_top_kernel(int* __restrict__ blocksum,
                                int* __restrict__ base) {
    int lane = threadIdx.x;           // 0..63
    int v = (lane < SCAN_BLOCKS) ? blocksum[lane] : 0;
    int inc = v;
    #pragma unroll
    for (int off = 1; off < 64; off <<= 1) {
        int n = __shfl_up(inc, off, 64);
        if (lane >= off) inc += n;
    }
    if (lane < SCAN_BLOCKS) blocksum[lane] = inc - v;   // exclusive
    if (lane == 0) base[NN] = NE;
}

// phase 3: block-local exclusive scan + offset -> base, cursor
__global__ void scan_fin_kernel(const int* __restrict__ counts,
                                const int* __restrict__ blockoff,
                                int* __restrict__ base,
                                int* __restrict__ cursor) {
    __shared__ int wsum[4];
    int b = blockIdx.x, t = threadIdx.x;
    int4 v = ((const int4*)counts)[b * 256 + t];
    int s = v.x + v.y + v.z + v.w;
    int lane = t & 63, wid = t >> 6;
    int inc = s;
    #pragma unroll
    for (int off = 1; off < 64; off <<= 1) {
        int n = __shfl_up(inc, off, 64);
        if (lane >= off) inc += n;
    }
    if (lane == 63) wsum[wid] = inc;
    __syncthreads();
    int add = blockoff[b];
    for (int w = 0; w < wid; ++w) add += wsum[w];
    int e0 = inc - s + add;
    int e1 = e0 + v.x;
    int e2 = e1 + v.y;
    int e3 = e2 + v.z;
    int idx = b * 1024 + t * 4;
    if (idx + 0 < NN) { base[idx + 0] = e0; cursor[idx + 0] = e0; }
    if (idx + 1 < NN) { base[idx + 1] = e1; cursor[idx + 1] = e1; }
    if (idx + 2 < NN) { base[idx + 2] = e2; cursor[idx + 2] = e2; }
    if (idx + 3 < NN) { base[idx + 3] = e3; cursor[idx + 3] = e3; }
}

// fused: [0..EBLK): one 64B record scatter per edge (single line touch)
//        [EBLK..EBLK+NBLK): x = nf copy + svb = packed pre(x)
__global__ void prep_kernel(const int* __restrict__ ei,
                            const float* __restrict__ emb,
                            const float* __restrict__ eattr,
                            const float* __restrict__ Wr1,   // [2][8][8]
                            int* __restrict__ cursor,
                            uint4* __restrict__ rec,
                            const float* __restrict__ nf,
                            const float* __restrict__ W0,
                            const float* __restrict__ W1,
                            float* __restrict__ x,
                            unsigned* __restrict__ svb) {
    __shared__ float wr1s[128];
    __shared__ float xs[8][128];
    int t = threadIdx.x;
    int b = blockIdx.x;
    if (b < EBLK) {
        if (t < 128) wr1s[t] = Wr1[t];
        __syncthreads();
        int e = b * 256 + t;
        int src = ei[e];
        int dst = ei[NE + e];
        int pos = atomicAdd(&cursor[dst], 1);

        const float4* s4 = (const float4*)emb + (size_t)e * 2;
        float4 a = s4[0], bb = s4[1];
        float em[8] = {a.x, a.y, a.z, a.w, bb.x, bb.y, bb.z, bb.w};
        float h0[8], h1[8];
        #pragma unroll
        for (int j = 0; j < 8; ++j) {
            float acc0 = 0.f, acc1 = 0.f;
            #pragma unroll
            for (int k = 0; k < 8; ++k) {
                acc0 = fmaf(em[k], wr1s[k * 8 + j], acc0);
                acc1 = fmaf(em[k], wr1s[64 + k * 8 + j], acc1);
            }
            h0[j] = silu_f(acc0);
            h1[j] = silu_f(acc1);
        }
        uint4 u0, u1;
        u0.x = bf16rn(h0[0]) | (bf16rn(h0[1]) << 16);
        u0.y = bf16rn(h0[2]) | (bf16rn(h0[3]) << 16);
        u0.z = bf16rn(h0[4]) | (bf16rn(h0[5]) << 16);
        u0.w = bf16rn(h0[6]) | (bf16rn(h0[7]) << 16);
        u1.x = bf16rn(h1[0]) | (bf16rn(h1[1]) << 16);
        u1.y = bf16rn(h1[2]) | (bf16rn(h1[3]) << 16);
        u1.z = bf16rn(h1[4]) | (bf16rn(h1[5]) << 16);
        u1.w = bf16rn(h1[6]) | (bf16rn(h1[7]) << 16);
        uint4* r = rec + (size_t)pos * 4;
        r[0] = u0;
        r[1] = u1;
        r[2] = ((const uint4*)eattr)[e];
        r[3] = make_uint4((unsigned)src, 0u, 0u, 0u);
    } else {
        int node0 = (b - EBLK) * 8;
        #pragma unroll
        for (int k = 0; k < 4; ++k) {
            int idx = t + k * 256;
            int n = idx >> 7, col = idx & 127;
            float val = nf[(size_t)(node0 + n) * 128 + col];
            xs[n][col] = val;
            x[(size_t)(node0 + n) * 128 + col] = val;
        }
        __syncthreads();
        int n = t >> 5, f = t & 31;
        int gn = node0 + n;
        float acc_s = 0.f, a0 = 0.f, a1 = 0.f, a2 = 0.f;
        #pragma unroll
        for (int c = 0; c < Cc; ++c) {
            float w0 = W0[c * Cc + f];
            float w1 = W1[c * Cc + f];
            acc_s = fmaf(xs[n][c], w0, acc_s);
            a0 = fmaf(xs[n][32 + c * 3 + 0], w1, a0);
            a1 = fmaf(xs[n][32 + c * 3 + 1], w1, a1);
            a2 = fmaf(xs[n][32 + c * 3 + 2], w1, a2);
        }
        unsigned* o = svb + (size_t)gn * 64;
        o[f]      = bf16rn(acc_s) | (bf16rn(a0) << 16);
        o[32 + f] = bf16rn(a1)    | (bf16rn(a2) << 16);
    }
}

// process one edge: h packed bf16 in ua, Y f32, sv unpacked
#define PROC_EDGE_PK(ua, Yv, se, v0, v1, v2)                                 \
    do {                                                                     \
        float hh0 = __uint_as_float(ua.x << 16);                             \
        float hh1 = __uint_as_float(ua.x & 0xffff0000u);                     \
        float hh2 = __uint_as_float(ua.y << 16);                             \
        float hh3 = __uint_as_float(ua.y & 0xffff0000u);                     \
        float hh4 = __uint_as_float(ua.z << 16);                             \
        float hh5 = __uint_as_float(ua.z & 0xffff0000u);                     \
        float hh6 = __uint_as_float(ua.w << 16);                             \
        float hh7 = __uint_as_float(ua.w & 0xffff0000u);                     \
        float w1 = 0.f, w2 = 0.f, w3 = 0.f, w4 = 0.f, w5 = 0.f;              \
        w1 = fmaf(hh0, wr2s[0][c], w1); w2 = fmaf(hh0, wr2s[0][32 + c], w2); \
        w3 = fmaf(hh0, wr2s[0][64 + c], w3); w4 = fmaf(hh0, wr2s[0][96 + c], w4); \
        w5 = fmaf(hh0, wr2s[0][128 + c], w5);                                \
        w1 = fmaf(hh1, wr2s[1][c], w1); w2 = fmaf(hh1, wr2s[1][32 + c], w2); \
        w3 = fmaf(hh1, wr2s[1][64 + c], w3); w4 = fmaf(hh1, wr2s[1][96 + c], w4); \
        w5 = fmaf(hh1, wr2s[1][128 + c], w5);                                \
        w1 = fmaf(hh2, wr2s[2][c], w1); w2 = fmaf(hh2, wr2s[2][32 + c], w2); \
        w3 = fmaf(hh2, wr2s[2][64 + c], w3); w4 = fmaf(hh2, wr2s[2][96 + c], w4); \
        w5 = fmaf(hh2, wr2s[2][128 + c], w5);                                \
        w1 = fmaf(hh3, wr2s[3][c], w1); w2 = fmaf(hh3, wr2s[3][32 + c], w2); \
        w3 = fmaf(hh3, wr2s[3][64 + c], w3); w4 = fmaf(hh3, wr2s[3][96 + c], w4); \
        w5 = fmaf(hh3, wr2s[3][128 + c], w5);                                \
        w1 = fmaf(hh4, wr2s[4][c], w1); w2 = fmaf(hh4, wr2s[4][32 + c], w2); \
        w3 = fmaf(hh4, wr2s[4][64 + c], w3); w4 = fmaf(hh4, wr2s[4][96 + c], w4); \
        w5 = fmaf(hh4, wr2s[4][128 + c], w5);                                \
        w1 = fmaf(hh5, wr2s[5][c], w1); w2 = fmaf(hh5, wr2s[5][32 + c], w2); \
        w3 = fmaf(hh5, wr2s[5][64 + c], w3); w4 = fmaf(hh5, wr2s[5][96 + c], w4); \
        w5 = fmaf(hh5, wr2s[5][128 + c], w5);                                \
        w1 = fmaf(hh6, wr2s[6][c], w1); w2 = fmaf(hh6, wr2s[6][32 + c], w2); \
        w3 = fmaf(hh6, wr2s[6][64 + c], w3); w4 = fmaf(hh6, wr2s[6][96 + c], w4); \
        w5 = fmaf(hh6, wr2s[6][128 + c], w5);                                \
        w1 = fmaf(hh7, wr2s[7][c], w1); w2 = fmaf(hh7, wr2s[7][32 + c], w2); \
        w3 = fmaf(hh7, wr2s[7][64 + c], w3); w4 = fmaf(hh7, wr2s[7][96 + c], w4); \
        w5 = fmaf(hh7, wr2s[7][128 + c], w5);                                \
        float dot = v0 * Yv.y + v1 * Yv.z + v2 * Yv.w;                       \
        ms += w1 * se * Yv.x + w4 * dot;                                     \
        float cx = v1 * Yv.w - v2 * Yv.z;                                    \
        float cy = v2 * Yv.y - v0 * Yv.w;                                    \
        float cz = v0 * Yv.z - v1 * Yv.y;                                    \
        mv0 += w2 * se * Yv.y + w3 * v0 * Yv.x + w5 * cx;                    \
        mv1 += w2 * se * Yv.z + w3 * v1 * Yv.x + w5 * cy;                    \
        mv2 += w2 * se * Yv.w + w3 * v2 * Yv.x + w5 * cz;                    \
    } while (0)

#define UNPACK_SV(p, se, v0, v1, v2)                                         \
    unsigned ulo_##se = (p)[c], uhi_##se = (p)[32 + c];                      \
    float se = __uint_as_float(ulo_##se << 16);                              \
    float v0 = __uint_as_float(ulo_##se & 0xffff0000u);                      \
    float v1 = __uint_as_float(uhi_##se << 16);                              \
    float v2 = __uint_as_float(uhi_##se & 0xffff0000u)

// one 32-lane group per dst node; 64B records (sequential), packed-bf16 sv
__global__ void agg_kernel(const int* __restrict__ base,
                           const uint4* __restrict__ rec,
                           const int lsel,
                           const unsigned* __restrict__ svb,
                           const float* __restrict__ Wr2,
                           float* __restrict__ agg) {
    __shared__ float wr2s[8][160];
    int t = threadIdx.x;
    for (int i = t; i < 8 * 160; i += 256) ((float*)wr2s)[i] = Wr2[i];
    __syncthreads();
    int n = blockIdx.x * 8 + (t >> 5);
    int c = t & 31;
    int jb = base[n], je = base[n + 1];
    float ms = 0.f, mv0 = 0.f, mv1 = 0.f, mv2 = 0.f;

    int j = jb;
    for (; j + 1 < je; j += 2) {
        const uint4* rA = rec + (size_t)j * 4;
        const uint4* rB = rA + 4;
        uint4 uA = rA[lsel];
        float4 YA = *(const float4*)(rA + 2);
        int srcA = (int)rA[3].x;
        uint4 uB = rB[lsel];
        float4 YB = *(const float4*)(rB + 2);
        int srcB = (int)rB[3].x;
        const unsigned* pA = svb + (size_t)srcA * 64;
        const unsigned* pB = svb + (size_t)srcB * 64;
        UNPACK_SV(pA, seA, vA0, vA1, vA2);
        UNPACK_SV(pB, seB, vB0, vB1, vB2);
        PROC_EDGE_PK(uA, YA, seA, vA0, vA1, vA2);
        PROC_EDGE_PK(uB, YB, seB, vB0, vB1, vB2);
    }
    if (j < je) {
        const uint4* rA = rec + (size_t)j * 4;
        uint4 uA = rA[lsel];
        float4 YA = *(const float4*)(rA + 2);
        int srcA = (int)rA[3].x;
        const unsigned* pA = svb + (size_t)srcA * 64;
        UNPACK_SV(pA, seA, vA0, vA1, vA2);
        PROC_EDGE_PK(uA, YA, seA, vA0, vA1, vA2);
    }

    float* ap = agg + (size_t)n * 128;
    ap[c]      = ms * DEG_INV;
    ap[32 + c] = mv0 * DEG_INV;
    ap[64 + c] = mv1 * DEG_INV;
    ap[96 + c] = mv2 * DEG_INV;
}

// node_post (+ optional next-layer node_pre), 16 nodes/block, 128 threads,
// 4 nodes/thread (n = g + k*4, g in 0..3). LDS 16KB -> ~10 blocks/CU.
template <int WANT_SV>
__global__ void post_pre_kernel(float* __restrict__ x,
                                const float* __restrict__ attrs,
                                const float* __restrict__ agg,
                                const float* __restrict__ Ws,
                                const float* __restrict__ Wv,
                                const float* __restrict__ Wsc_s,
                                const float* __restrict__ Wsc_v,
                                const float* __restrict__ W0n,
                                const float* __restrict__ W1n,
                                unsigned* __restrict__ svb) {
    __shared__ float shx[16][128];   // x, interleaved
    __shared__ float sha[16][128];   // agg, planar
    int t = threadIdx.x;
    int node0 = blockIdx.x * 16;
    #pragma unroll
    for (int k = 0; k < 4; ++k) {
        int f4 = t + k * 128;          // 0..511 float4 slots (16 nodes x 32)
        int n = f4 >> 5, col4 = f4 & 31;
        int gn = node0 + n;
        if (gn < NN) {
            ((float4*)&shx[n][0])[col4] = ((const float4*)(x + (size_t)gn * 128))[col4];
            ((float4*)&sha[n][0])[col4] = ((const float4*)(agg + (size_t)gn * 128))[col4];
        }
    }
    __syncthreads();
    int g = t >> 5, f = t & 31;        // g in 0..3

    float az[4][4];
    #pragma unroll
    for (int k = 0; k < 4; ++k) {
        int gn = node0 + g + k * 4;
        if (gn < NN) {
            float4 a4 = ((const float4*)attrs)[gn];
            az[k][0] = a4.x; az[k][1] = a4.y; az[k][2] = a4.z; az[k][3] = a4.w;
        } else {
            az[k][0] = az[k][1] = az[k][2] = az[k][3] = 0.f;
        }
    }

    float os0[4] = {0, 0, 0, 0}, os1[4] = {0, 0, 0, 0};
    float ov0[4] = {0, 0, 0, 0}, ov1[4] = {0, 0, 0, 0}, ov2[4] = {0, 0, 0, 0};

    #pragma unroll 2
    for (int c = 0; c < Cc; ++c) {
        float ws0 = Ws[c * 64 + f];
        float ws1 = Ws[c * 64 + 32 + f];
        float wv  = Wv[c * 32 + f];
        #pragma unroll
        for (int k = 0; k < 4; ++k) {
            int n = g + k * 4;
            float as  = sha[n][c];
            float av0 = sha[n][32 + c];
            float av1 = sha[n][64 + c];
            float av2 = sha[n][96 + c];
            os0[k] = fmaf(as, ws0, os0[k]);
            os1[k] = fmaf(as, ws1, os1[k]);
            ov0[k] = fmaf(av0, wv, ov0[k]);
            ov1[k] = fmaf(av1, wv, ov1[k]);
            ov2[k] = fmaf(av2, wv, ov2[k]);
        }
        #pragma unroll
        for (int z = 0; z < 4; ++z) {
            int cz = c * 4 + z;
            float wss0 = Wsc_s[cz * 64 + f];
            float wss1 = Wsc_s[cz * 64 + 32 + f];
            float wsv  = Wsc_v[cz * 32 + f];
            #pragma unroll
            for (int k = 0; k < 4; ++k) {
                int n = g + k * 4;
                float azv = az[k][z];
                float sa = shx[n][c] * azv;
                os0[k] = fmaf(sa, wss0, os0[k]);
                os1[k] = fmaf(sa, wss1, os1[k]);
                float va = azv * wsv;
                ov0[k] = fmaf(shx[n][32 + c * 3 + 0], va, ov0[k]);
                ov1[k] = fmaf(shx[n][32 + c * 3 + 1], va, ov1[k]);
                ov2[k] = fmaf(shx[n][32 + c * 3 + 2], va, ov2[k]);
            }
        }
    }

    float ns[4], nv0[4], nv1[4], nv2[4];
    #pragma unroll
    for (int k = 0; k < 4; ++k) {
        int n = g + k * 4;
        int gn = node0 + n;
        float feat = ssp_f(os0[k]);
        float gate = ssp_f(os1[k]);
        ns[k]  = shx[n][f] + feat;
        nv0[k] = shx[n][32 + f * 3 + 0] + ov0[k] * gate;
        nv1[k] = shx[n][32 + f * 3 + 1] + ov1[k] * gate;
        nv2[k] = shx[n][32 + f * 3 + 2] + ov2[k] * gate;
        if (gn < NN) {
            float* xp = x + (size_t)gn * 128;
            xp[f] = ns[k];
            xp[32 + f * 3 + 0] = nv0[k];
            xp[32 + f * 3 + 1] = nv1[k];
            xp[32 + f * 3 + 2] = nv2[k];
        }
    }

    if (WANT_SV) {
        __syncthreads();
        #pragma unroll
        for (int k = 0; k < 4; ++k) {
            int n = g + k * 4;
            sha[n][f] = ns[k];
            sha[n][32 + f * 3 + 0] = nv0[k];
            sha[n][32 + f * 3 + 1] = nv1[k];
            sha[n][32 + f * 3 + 2] = nv2[k];
        }
        __syncthreads();
        float bs[4] = {0, 0, 0, 0};
        float b0[4] = {0, 0, 0, 0}, b1[4] = {0, 0, 0, 0}, b2[4] = {0, 0, 0, 0};
        #pragma unroll 4
        for (int c = 0; c < Cc; ++c) {
            float w0 = W0n[c * Cc + f];
            float w1 = W1n[c * Cc + f];
            #pragma unroll
            for (int k = 0; k < 4; ++k) {
                int n = g + k * 4;
                bs[k] = fmaf(sha[n][c], w0, bs[k]);
                b0[k] = fmaf(sha[n][32 + c * 3 + 0], w1, b0[k]);
                b1[k] = fmaf(sha[n][32 + c * 3 + 1], w1, b1[k]);
                b2[k] = fmaf(sha[n][32 + c * 3 + 2], w1, b2[k]);
            }
        }
        #pragma unroll
        for (int k = 0; k < 4; ++k) {
            int gn = node0 + g + k * 4;
            if (gn < NN) {
                unsigned* o = svb + (size_t)gn * 64;
                o[f]      = bf16rn(bs[k]) | (bf16rn(b0[k]) << 16);
                o[32 + f] = bf16rn(b1[k]) | (bf16rn(b2[k]) << 16);
            }
        }
    }
}

// fallback (atomic) edge kernel — packed svb, planar agg
__global__ void edge_atomic_kernel(const int* __restrict__ ei,
                                   const float* __restrict__ emb,
                                   const float* __restrict__ eattr,
                                   const unsigned* __restrict__ svb,
                                   const float* __restrict__ Wr1,
                                   const float* __restrict__ Wr2,
                                   float* __restrict__ agg) {
    int t = threadIdx.x;
    int eg = t >> 5;
    int c = t & 31;
    int e = blockIdx.x * 8 + eg;
    if (e >= NE) return;
    int src = ei[e];
    int dst = ei[NE + e];
    float h = 0.f;
    if (c < 8) {
        #pragma unroll
        for (int k = 0; k < 8; ++k)
            h = fmaf(emb[e * 8 + k], Wr1[k * 8 + c], h);
        h = silu_f(h);
    }
    float w1 = 0.f, w2 = 0.f, w3 = 0.f, w4 = 0.f, w5 = 0.f;
    #pragma unroll
    for (int j = 0; j < 8; ++j) {
        float hj = __shfl(h, j, 32);
        const float* wr = Wr2 + j * 160;
        w1 = fmaf(hj, wr[c], w1);
        w2 = fmaf(hj, wr[32 + c], w2);
        w3 = fmaf(hj, wr[64 + c], w3);
        w4 = fmaf(hj, wr[96 + c], w4);
        w5 = fmaf(hj, wr[128 + c], w5);
    }
    float Y0  = eattr[e * 4 + 0];
    float Yv0 = eattr[e * 4 + 1];
    float Yv1 = eattr[e * 4 + 2];
    float Yv2 = eattr[e * 4 + 3];
    const unsigned* p = svb + (size_t)src * 64;
    unsigned ulo = p[c], uhi = p[32 + c];
    float se  = __uint_as_float(ulo << 16);
    float ve0 = __uint_as_float(ulo & 0xffff0000u);
    float ve1 = __uint_as_float(uhi << 16);
    float ve2 = __uint_as_float(uhi & 0xffff0000u);
    float dot = ve0 * Yv0 + ve1 * Yv1 + ve2 * Yv2;
    float msg = (w1 * se * Y0 + w4 * dot) * DEG_INV;
    float cx = ve1 * Yv2 - ve2 * Yv1;
    float cy = ve2 * Yv0 - ve0 * Yv2;
    float cz = ve0 * Yv1 - ve1 * Yv0;
    float mv0 = (w2 * se * Yv0 + w3 * ve0 * Y0 + w5 * cx) * DEG_INV;
    float mv1 = (w2 * se * Yv1 + w3 * ve1 * Y0 + w5 * cy) * DEG_INV;
    float mv2 = (w2 * se * Yv2 + w3 * ve2 * Y0 + w5 * cz) * DEG_INV;
    float* ap = agg + (size_t)dst * 128;
    atomicAdd(&ap[c], msg);
    atomicAdd(&ap[32 + c], mv0);
    atomicAdd(&ap[64 + c], mv1);
    atomicAdd(&ap[96 + c], mv2);
}

// fallback init (separate kernel, packed svb)
__global__ void init_kernel(const float* __restrict__ nf,
                            const float* __restrict__ W0,
                            const float* __restrict__ W1,
                            float* __restrict__ x,
                            unsigned* __restrict__ svb) {
    __shared__ float xs[8][128];
    int t = threadIdx.x;
    int node0 = blockIdx.x * 8;
    #pragma unroll
    for (int k = 0; k < 4; ++k) {
        int idx = t + k * 256;
        int n = idx >> 7, col = idx & 127;
        float val = nf[(size_t)(node0 + n) * 128 + col];
        xs[n][col] = val;
        x[(size_t)(node0 + n) * 128 + col] = val;
    }
    __syncthreads();
    int n = t >> 5, f = t & 31;
    int gn = node0 + n;
    float acc_s = 0.f, a0 = 0.f, a1 = 0.f, a2 = 0.f;
    #pragma unroll
    for (int c = 0; c < Cc; ++c) {
        float w0 = W0[c * Cc + f];
        float w1 = W1[c * Cc + f];
        acc_s = fmaf(xs[n][c], w0, acc_s);
        a0 = fmaf(xs[n][32 + c * 3 + 0], w1, a0);
        a1 = fmaf(xs[n][32 + c * 3 + 1], w1, a1);
        a2 = fmaf(xs[n][32 + c * 3 + 2], w1, a2);
    }
    unsigned* o = svb + (size_t)gn * 64;
    o[f]      = bf16rn(acc_s) | (bf16rn(a0) << 16);
    o[32 + f] = bf16rn(a1)    | (bf16rn(a2) << 16);
}

extern "C" void kernel_launch(void* const* d_in, const int* in_sizes, int n_in,
                              void* d_out, int out_size, void* d_ws, size_t ws_size,
                              hipStream_t stream) {
    const float* node_features  = (const float*)d_in[0];
    const float* node_attrs     = (const float*)d_in[1];
    const int*   edge_index     = (const int*)d_in[2];
    const float* edge_embedding = (const float*)d_in[3];
    const float* edge_attrs     = (const float*)d_in[4];
    const float* W0    = (const float*)d_in[5];
    const float* W1    = (const float*)d_in[6];
    const float* Wr1   = (const float*)d_in[7];
    const float* Wr2   = (const float*)d_in[8];
    const float* Ws    = (const float*)d_in[9];
    const float* Wv    = (const float*)d_in[10];
    const float* Wsc_s = (const float*)d_in[11];
    const float* Wsc_v = (const float*)d_in[12];

    float* x = (float*)d_out;

    float* ws = (float*)d_ws;
    unsigned* svb = (unsigned*)ws;                     // NN*64 uint (packed bf16)
    float* agg  = (float*)(svb + (size_t)NN * 64);     // NN*128 f32 (planar)
    uint4* rec  = (uint4*)(agg + (size_t)NN * 128);    // NE*4 uint4 (64B/edge)
    int* counts   = (int*)(rec + (size_t)NE * 4);      // SCAN_PAD
    int* base     = counts + SCAN_PAD;                 // NN+1
    int* cursor   = base + NN + 1;                     // NN
    int* blocksum = cursor + NN;                       // SCAN_BLOCKS
    size_t needed = ((char*)(blocksum + SCAN_BLOCKS)) - (char*)d_ws;

    bool use_sorted = ws_size >= needed;
    const int PP_GRID = (NN + 15) / 16;

    if (use_sorted) {
        hipMemsetAsync(counts, 0, SCAN_PAD * sizeof(int), stream);
        hist_kernel<<<NE / 256, 256, 0, stream>>>(edge_index, counts);
        scan_part_kernel<<<SCAN_BLOCKS, 256, 0, stream>>>(counts, blocksum);
        scan_top_kernel<<<1, 64, 0, stream>>>(blocksum, base);
        scan_fin_kernel<<<SCAN_BLOCKS, 256, 0, stream>>>(counts, blocksum,
                                                         base, cursor);
        prep_kernel<<<EBLK + NBLK, 256, 0, stream>>>(
            edge_index, edge_embedding, edge_attrs, Wr1,
            cursor, rec,
            node_features, W0, W1, x, svb);

        // layer 0
        agg_kernel<<<NN / 8, 256, 0, stream>>>(base, rec, 0, svb, Wr2, agg);
        post_pre_kernel<1><<<PP_GRID, 128, 0, stream>>>(
            x, node_attrs, agg, Ws, Wv, Wsc_s, Wsc_v,
            W0 + Cc * Cc, W1 + Cc * Cc, svb);
        // layer 1
        agg_kernel<<<NN / 8, 256, 0, stream>>>(base, rec, 1, svb,
                                               Wr2 + Bb * 5 * Cc, agg);
        post_pre_kernel<0><<<PP_GRID, 128, 0, stream>>>(
            x, node_attrs, agg,
            Ws + Cc * 2 * Cc, Wv + Cc * Cc,
            Wsc_s + Cc * Zz * 2 * Cc, Wsc_v + Cc * Zz * Cc,
            nullptr, nullptr, nullptr);
    } else {
        hipMemcpyAsync(x, node_features, (size_t)NN * 128 * sizeof(float),
                       hipMemcpyDeviceToDevice, stream);
        for (int l = 0; l < NL; ++l) {
            hipMemsetAsync(agg, 0, (size_t)NN * 128 * sizeof(float), stream);
            init_kernel<<<NN / 8, 256, 0, stream>>>(
                x, W0 + l * Cc * Cc, W1 + l * Cc * Cc, x, svb);
            edge_atomic_kernel<<<NE / 8, 256, 0, stream>>>(
                edge_index, edge_embedding, edge_attrs, svb,
                Wr1 + l * Bb * Bb, Wr2 + l * Bb * 5 * Cc, agg);
            post_pre_kernel<0><<<PP_GRID, 128, 0, stream>>>(
                x, node_attrs, agg,
                Ws + l * Cc * 2 * Cc, Wv + l * Cc * Cc,
                Wsc_s + l * Cc * Zz * 2 * Cc, Wsc_v + l * Cc * Zz * Cc,
                nullptr, nullptr, nullptr);
        }
    }
}